// Round 10
// baseline (78.559 us; speedup 1.0000x reference)
//
#include <hip/hip_runtime.h>
#include <math.h>

// Tropical max/min-plus pseudo-matmul — DIAGNOSTIC ROUND.
// out[b,u] = max_f(x[b,f] + w[f,u]) for u<128, min_f otherwise.
//
// R6-R9 plateau ~23-26us vs ~6-8us model; kernel never reaches the top-5
// counter table (fills are ~41us), so we have no measured counters for any
// clean kernel. max is IDEMPOTENT -> run the k-loop reps=2 times over the
// same data (bit-identical result) to push the dispatch to ~46us and surface
// VALUBusy / Occupancy / LDS-conflict / FETCH / VGPR for the real loop.
// Runtime trip count + memory clobber prevent the compiler from CSE'ing the
// second pass. Structure is exactly R9: BR=8, U=4/lane, 16-wave k-split
// (KW=32), per-lane sign fold, LDS x-broadcast, 1 block/CU.

#define FEAT  512
#define UNITS 256
#define BR    8     // rows per block
#define KW    32    // k per wave
#define NW    16    // waves per block

__device__ __forceinline__ float max3(float a, float b, float c) {
    return fmaxf(fmaxf(a, b), c);   // v_max3_f32
}

__global__ __launch_bounds__(1024, 1) void tropical_kernel(const float* __restrict__ x,
                                                           const float* __restrict__ w,
                                                           float* __restrict__ out,
                                                           int reps) {
    __shared__ float lds[NW * BR * UNITS];   // 128 KB; x tile uses first 16 KB
    const int tid  = threadIdx.x;
    const int lane = tid & 63;
    const int wv   = __builtin_amdgcn_readfirstlane(tid >> 6);  // 0..15
    const int u0   = lane * 4;                                  // 0..252
    const float sgn = (lane < 32) ? 1.0f : -1.0f;               // min half negated
    const int row0 = blockIdx.x * BR;
    const int kb   = wv * KW;

    // ---- stage x tile (8 rows x 512 = 16 KB), one float4 per thread ----
    {
        const float4* src = (const float4*)(x + (size_t)row0 * FEAT);
        ((float4*)lds)[tid] = src[tid];
    }

    const float* wp = w + (size_t)kb * UNITS + u0;   // dwordx4, 1KB/wave-instr

    float4 acc[BR];
    #pragma unroll
    for (int r = 0; r < BR; ++r)
        acc[r] = make_float4(-__builtin_inff(), -__builtin_inff(),
                             -__builtin_inff(), -__builtin_inff());

    __syncthreads();   // x tile visible

    // DIAGNOSTIC: reps passes over identical data; max is idempotent so the
    // result is bit-identical to one pass. Runtime trip count + clobber stop
    // the compiler from eliminating pass 2.
    #pragma unroll 1
    for (int rep = 0; rep < reps; ++rep) {
        #pragma unroll 1
        for (int q = 0; q < KW / 4; ++q) {
            float4 wq[4];
            #pragma unroll
            for (int k = 0; k < 4; ++k)
                wq[k] = *(const float4*)(wp + (size_t)(q * 4 + k) * UNITS);

            // fold per-lane sign into w once per quad (shared across 8 rows)
            const float4 w0 = make_float4(wq[0].x*sgn, wq[0].y*sgn, wq[0].z*sgn, wq[0].w*sgn);
            const float4 w1 = make_float4(wq[1].x*sgn, wq[1].y*sgn, wq[1].z*sgn, wq[1].w*sgn);
            const float4 w2 = make_float4(wq[2].x*sgn, wq[2].y*sgn, wq[2].z*sgn, wq[2].w*sgn);
            const float4 w3 = make_float4(wq[3].x*sgn, wq[3].y*sgn, wq[3].z*sgn, wq[3].w*sgn);

            #pragma unroll
            for (int r = 0; r < BR; ++r) {
                // broadcast ds_read_b128: all 64 lanes same address
                const float4 a = *(const float4*)&lds[r * FEAT + kb + q * 4];
                float4 A = acc[r];
                A.x = max3(A.x, fmaf(a.x, sgn, w0.x), fmaf(a.y, sgn, w1.x));
                A.x = max3(A.x, fmaf(a.z, sgn, w2.x), fmaf(a.w, sgn, w3.x));
                A.y = max3(A.y, fmaf(a.x, sgn, w0.y), fmaf(a.y, sgn, w1.y));
                A.y = max3(A.y, fmaf(a.z, sgn, w2.y), fmaf(a.w, sgn, w3.y));
                A.z = max3(A.z, fmaf(a.x, sgn, w0.z), fmaf(a.y, sgn, w1.z));
                A.z = max3(A.z, fmaf(a.z, sgn, w2.z), fmaf(a.w, sgn, w3.z));
                A.w = max3(A.w, fmaf(a.x, sgn, w0.w), fmaf(a.y, sgn, w1.w));
                A.w = max3(A.w, fmaf(a.z, sgn, w2.w), fmaf(a.w, sgn, w3.w));
                acc[r] = A;
            }
        }
        __asm__ __volatile__("" ::: "memory");   // block cross-rep CSE/hoist
    }

    // ---- combine 16 k-partials via LDS (reuses x region; 128 KB) ----
    __syncthreads();   // all waves done reading x tile
    #pragma unroll
    for (int r = 0; r < BR; ++r)
        *(float4*)&lds[((wv * BR + r) * UNITS) + u0] = acc[r];
    __syncthreads();

    // thread -> output pair: r = tid>>7 (0..7), units up0..up0+1
    const int r   = tid >> 7;
    const int up0 = (tid & 127) * 2;
    float2 v = *(const float2*)&lds[(0 * BR + r) * UNITS + up0];
    #pragma unroll
    for (int j = 1; j < NW; ++j) {
        const float2 p = *(const float2*)&lds[(j * BR + r) * UNITS + up0];
        v.x = fmaxf(v.x, p.x);
        v.y = fmaxf(v.y, p.y);
    }
    const float so = (up0 < 128) ? 1.0f : -1.0f;   // undo negation for min half
    *(float2*)&out[(size_t)(row0 + r) * UNITS + up0] = make_float2(v.x * so, v.y * so);
}

extern "C" void kernel_launch(void* const* d_in, const int* in_sizes, int n_in,
                              void* d_out, int out_size, void* d_ws, size_t ws_size,
                              hipStream_t stream) {
    const float* x = (const float*)d_in[0];   // (2048, 512)
    const float* w = (const float*)d_in[1];   // (512, 256)
    float* out = (float*)d_out;               // (2048, 256)

    // 256 blocks x 16 waves = 4096 waves = 4/SIMD, exactly 1 block per CU.
    // reps=2: idempotent double-pass purely to surface the kernel in the
    // rocprof top-5 (same work every call -> graph-capture safe).
    tropical_kernel<<<dim3(2048 / BR), dim3(1024), 0, stream>>>(x, w, out, 2);
}